// Round 4
// baseline (135.248 us; speedup 1.0000x reference)
//
#include <hip/hip_runtime.h>
#include <hip/hip_bf16.h>
#include <math.h>

// CrossGeometricStructureEmbedding, round 11.
// R10 post-mortem: dataflow confirmed (LDS conflict counter halved exactly:
// traffic 8->4 MB/CU) but execution failed: (a) spill (WRITE_SIZE +2.5MB;
// VGPR_Count=128 < af alone), (b) 2 MFMA chains at 2 waves/SIMD with no
// anti-phase block. R11 keeps the W-in-LDS / E-in-regs orientation and fixes:
// 256-thr blocks with (256,2) bounds (R7-proven ~230 regs spill-free),
// 2 independent blocks/CU; W staged in 64KB o-half chunks (4 rounds:
// d-h0, d-h1, a-h0, a-h1) so af (128 regs) is generated once per type and
// reused across halves (512 trans/wave, 4x less than R10); 4 MFMA chains
// (acc[2ntp][2mt]) so each ks = 2 b128 reads + 4 MFMAs (24:32 cy, MFMA-
// favorable); d-maxes in 8 regs/lane (no dm LDS). LDS floor ~49K cy
// (20.5us) + staging ~12K; predict 34-42us kernel. Key check: WRITE_SIZE
// must stay 4096 KB (no spill).

typedef __attribute__((ext_vector_type(8))) short short8;
typedef __attribute__((ext_vector_type(16))) float f32x16;
typedef __attribute__((ext_vector_type(4))) unsigned int uint4v;

#define HH 256
#define BPTS 4
#define NPTS 4096

__device__ __forceinline__ unsigned short f2bf(float f) {
    union { float f; unsigned int u; } v; v.f = f;
    unsigned int r = v.u + 0x7fffu + ((v.u >> 16) & 1u);  // RNE
    return (unsigned short)(r >> 16);
}

__device__ __forceinline__ unsigned int pack_sc(float s, float c) {
    union { __hip_bfloat162 h; unsigned int u; } v;
    v.h = __float22bfloat162_rn(make_float2(s, c));  // low = sin, high = cos
    return v.u;
}

__global__ __launch_bounds__(256)
void prep_w_kernel(const float* __restrict__ Wa, const float* __restrict__ Wd,
                   unsigned short* __restrict__ wbf) {
    int i = blockIdx.x * 256 + threadIdx.x;
    if (i < HH * HH) {
        wbf[i] = f2bf(Wd[i]);             // [0, 65536): Wd bf16
        wbf[HH * HH + i] = f2bf(Wa[i]);   // [65536, 131072): Wa bf16
    }
}

// Wlds swizzle: 16B chunk ch of local row o lives at byte offset
//   o*512 + ((ch ^ (o&7)) << 4)
// Read side XOR-decomposes: (o<<9) ^ ((o&7)<<4) ^ (half<<4) ^ (ks<<5).
// R10 measured this pattern at the intrinsic 4cy/b128 floor (no real
// conflicts), so it carries over verbatim.

__global__ __launch_bounds__(256, 2)
void cgse_main(const float* __restrict__ points,
               const float* __restrict__ anchors,
               const unsigned short* __restrict__ wbf,
               const float* __restrict__ ba,
               const float* __restrict__ bd,
               float* __restrict__ out) {
    __shared__ __align__(16) unsigned short Wlds[128 * HH];  // 64 KB (o-half)
    __shared__ float xs[2][BPTS][64];                        // 2 KB
    __shared__ float anch[192];

    const int tid = threadIdx.x;
    const int wave = tid >> 6, lane = tid & 63;
    const int l5 = lane & 31, half = lane >> 5;
    const int base = blockIdx.x * BPTS;
    const int pt = wave;  // 1 point per wave

    // ---- geometry: 4 pts x 64 anchors = 256 tasks / 256 threads
    if (tid < 192) anch[tid] = anchors[tid];
    __syncthreads();
    {
        const int k = lane, k2 = (lane + 1) & 63;
        const int pn = base + wave;
        const float px = points[pn * 3 + 0], py = points[pn * 3 + 1], pz = points[pn * 3 + 2];
        const float r1x = px - anch[k * 3 + 0];
        const float r1y = py - anch[k * 3 + 1];
        const float r1z = pz - anch[k * 3 + 2];
        const float r2x = px - anch[k2 * 3 + 0];
        const float r2y = py - anch[k2 * 3 + 1];
        const float r2z = pz - anch[k2 * 3 + 2];
        xs[0][wave][k] = sqrtf(r1x * r1x + r1y * r1y + r1z * r1z) * 5.0f;  // /SIGMA_D
        const float cx = r1y * r2z - r1z * r2y;
        const float cy = r1z * r2x - r1x * r2z;
        const float cz = r1x * r2y - r1y * r2x;
        const float sv = sqrtf(cx * cx + cy * cy + cz * cz);
        const float cv = r1x * r2x + r1y * r2y + r1z * r2z;
        xs[1][wave][k] = atan2f(sv, cv) * 3.8197186342054885f;  // *180/(15*pi)
    }

    // per-lane bias for each of the 8 (h,nn,ntp) column groups
    float bias[8];
    #pragma unroll
    for (int i = 0; i < 8; ++i) {
        const int c = (i >> 2) * 128 + ((i >> 1) & 1) * 64 + (i & 1) * 32 + l5;
        bias[i] = ba[c] + bd[c];
    }

    float dmr[8];  // d-pass maxes, valid on lanes 0..31

    const char* wbyte = (const char*)wbf;

    #pragma unroll 1
    for (int t = 0; t < 2; ++t) {  // 0 = d (Wd), 1 = a (Wa)
        // ---- A-gen for type t: E-frags into 128 regs, reused across both
        // o-halves. A-frag lane layout (32x32x16): row = anchor = mt*32+l5,
        // k = 8*half + j -> element E[anchor][16ks+8half+j]; pair p =
        // 8ks+4half+(j>>1), low=sin/high=cos (R10-verified mapping).
        short8 af[2][16];
        #pragma unroll
        for (int mt = 0; mt < 2; ++mt) {
            const float x = xs[t][pt][mt * 32 + l5];
            // (1/2pi) * 10^(-half/8); per-ks factor 10^(-8/32)
            float t0 = x * (half ? 0.11936620731892151f : 0.15915494309189535f);
            #pragma unroll
            for (int ks = 0; ks < 16; ++ks) {
                const float t1 = t0 * 0.9305720409297085f;   // 10^-1/32
                const float t2 = t0 * 0.8659643233600653f;   // 10^-2/32
                const float t3 = t0 * 0.8058421877614819f;   // 10^-3/32
                uint4v w;
                w[0] = pack_sc(__builtin_amdgcn_sinf(t0), __builtin_amdgcn_cosf(t0));
                w[1] = pack_sc(__builtin_amdgcn_sinf(t1), __builtin_amdgcn_cosf(t1));
                w[2] = pack_sc(__builtin_amdgcn_sinf(t2), __builtin_amdgcn_cosf(t2));
                w[3] = pack_sc(__builtin_amdgcn_sinf(t3), __builtin_amdgcn_cosf(t3));
                af[mt][ks] = *(short8*)&w;
                t0 *= 0.5623413251903491f;                   // 10^-8/32
            }
        }

        #pragma unroll
        for (int h = 0; h < 2; ++h) {  // o-half
            __syncthreads();  // all reads of previous Wlds content retired
            // ---- stage W[t] rows [128h, 128h+128) : 4096 16B chunks / 256 thr.
            {
                const uint4v* __restrict__ src =
                    (const uint4v*)(wbyte + t * 131072 + h * 65536);
                #pragma unroll
                for (int it = 0; it < 16; ++it) {
                    const int c = it * 256 + tid;
                    const uint4v v = src[c];
                    const int o = c >> 5, ch = c & 31;
                    *(uint4v*)((char*)Wlds + o * 512 + (((ch ^ (o & 7)) & 31) << 4)) = v;
                }
            }
            __syncthreads();

            #pragma unroll
            for (int nn = 0; nn < 2; ++nn) {  // pair of 32-col tiles
                int rb[2];
                #pragma unroll
                for (int ntp = 0; ntp < 2; ++ntp) {
                    const int ol = (nn * 2 + ntp) * 32 + l5;
                    rb[ntp] = (ol << 9) ^ ((ol & 7) << 4) ^ (half << 4);
                }
                f32x16 acc[2][2];  // [ntp][mt], 4 independent chains
                #pragma unroll
                for (int ntp = 0; ntp < 2; ++ntp)
                    #pragma unroll
                    for (int mt = 0; mt < 2; ++mt)
                        #pragma unroll
                        for (int r = 0; r < 16; ++r) acc[ntp][mt][r] = 0.f;

                #pragma unroll
                for (int ks = 0; ks < 16; ++ks) {
                    const short8 b0 = *(const short8*)((char*)Wlds + (rb[0] ^ (ks << 5)));
                    const short8 b1 = *(const short8*)((char*)Wlds + (rb[1] ^ (ks << 5)));
                    acc[0][0] = __builtin_amdgcn_mfma_f32_32x32x16_bf16(af[0][ks], b0, acc[0][0], 0, 0, 0);
                    acc[0][1] = __builtin_amdgcn_mfma_f32_32x32x16_bf16(af[1][ks], b0, acc[0][1], 0, 0, 0);
                    acc[1][0] = __builtin_amdgcn_mfma_f32_32x32x16_bf16(af[0][ks], b1, acc[1][0], 0, 0, 0);
                    acc[1][1] = __builtin_amdgcn_mfma_f32_32x32x16_bf16(af[1][ks], b1, acc[1][1], 0, 0, 0);
                }

                // epilogue: max over 64 anchors. C/D layout: col = o = l5
                // (in-lane!), rows = anchors via rowmap(reg, half); fmax over
                // mt merges anchors a / a+32, reg-tree over 16, shfl_down(32)
                // merges lane-halves (same col). Valid on lanes 0..31.
                #pragma unroll
                for (int ntp = 0; ntp < 2; ++ntp) {
                    float t8[8];
                    #pragma unroll
                    for (int r = 0; r < 8; ++r)
                        t8[r] = fmaxf(fmaxf(acc[ntp][0][2 * r], acc[ntp][0][2 * r + 1]),
                                      fmaxf(acc[ntp][1][2 * r], acc[ntp][1][2 * r + 1]));
                    const float ta = fmaxf(fmaxf(t8[0], t8[1]), fmaxf(t8[2], t8[3]));
                    const float tb = fmaxf(fmaxf(t8[4], t8[5]), fmaxf(t8[6], t8[7]));
                    float m = fmaxf(ta, tb);
                    m = fmaxf(m, __shfl_down(m, 32));
                    const int idx = h * 4 + nn * 2 + ntp;  // static
                    if (t == 0) {
                        dmr[idx] = m;
                    } else if (lane < 32) {
                        out[(base + pt) * HH + h * 128 + nn * 64 + ntp * 32 + l5]
                            = m + dmr[idx] + bias[idx];
                    }
                }
            }
        }
    }
}

extern "C" void kernel_launch(void* const* d_in, const int* in_sizes, int n_in,
                              void* d_out, int out_size, void* d_ws, size_t ws_size,
                              hipStream_t stream) {
    const float* points  = (const float*)d_in[0];
    const float* anchors = (const float*)d_in[1];
    // d_in[2] = cor_score: unused by the reference
    const float* Wa = (const float*)d_in[3];
    const float* ba = (const float*)d_in[4];
    const float* Wd = (const float*)d_in[5];
    const float* bd = (const float*)d_in[6];

    unsigned short* wbf = (unsigned short*)d_ws;  // 256 KB: Wd|Wa bf16

    hipLaunchKernelGGL(prep_w_kernel, dim3(256), dim3(256), 0, stream, Wa, Wd, wbf);
    hipLaunchKernelGGL(cgse_main, dim3(NPTS / BPTS), dim3(256), 0, stream,
                       points, anchors, wbf, ba, bd, (float*)d_out);
}

// Round 5
// 120.595 us; speedup vs baseline: 1.1215x; 1.1215x over previous
//
#include <hip/hip_runtime.h>
#include <hip/hip_bf16.h>
#include <math.h>

// CrossGeometricStructureEmbedding, round 12.
// R9/R10/R11 post-mortem: every attempt to hold the E tile in registers
// spills (compiler won't carry a 128-reg array across staging loads);
// family abandoned. R8 (66.3us, VGPR 64, spill-free) is the base, and its
// binding resource is the LDS read pipe: 8.4 MB/CU at 85 B/cy = 41us of a
// 66us kernel. R12 shrinks the problem instead of the schedule: for pairs
// i>=76, z = x*d_i <= 0.19 rad (x <= ~45, d_i = 10^(-i/32)), so
// sin(z)=z (err z^3/6 <= 1e-3) and cos(z)=1-z^2/2 (err z^4/24 <= 6e-5).
// Pairs 76..127 (104 of 256 K-elems) fold into 3 augmented K-columns
// [x, x^2, 1] with per-column weights u,c2,v precomputed in prep:
//   u[o]  = sum_{i>=76} d_i * W[o][2i]
//   c2[o] = sum_{i>=76} -(d_i^2/2) * W[o][2i+1]
//   v[o]  = sum_{i>=76} W[o][2i+1]
// K: 256 -> 160 (10 ks steps). LDS traffic and MFMA work x0.625 ->
// read floor 26us. All R8-verified mappings (swizzle, fragment layouts,
// epilogue, dms) unchanged; only loop bounds, fill chunk table, and prep
// change. bw drops to 40 regs. Expected output error <= ~1e-3.

typedef __attribute__((ext_vector_type(8))) short short8;
typedef __attribute__((ext_vector_type(16))) float f32x16;
typedef __attribute__((ext_vector_type(4))) unsigned int uint4v;

#define HH 256
#define KK 160
#define P_PTS 8
#define NPTS 4096

__device__ __forceinline__ unsigned short f2bf(float f) {
    union { float f; unsigned int u; } v; v.f = f;
    unsigned int r = v.u + 0x7fffu + ((v.u >> 16) & 1u);  // RNE
    return (unsigned short)(r >> 16);
}

__device__ __forceinline__ unsigned int pack_sc(float s, float c) {
    union { __hip_bfloat162 h; unsigned int u; } v;
    v.h = __float22bfloat162_rn(make_float2(s, c));  // low = even elem, high = odd
    return v.u;
}

// Build trimmed+augmented W: wbf[(t*256+o)*160 + e]
//   e in [0,152): W[o][e] bf16 (pairs 0..75)
//   e=152: u[o]; e=153: c2[o]; e=154: v[o]; e in [155,160): 0
__global__ __launch_bounds__(256)
void prep_w_kernel(const float* __restrict__ Wa, const float* __restrict__ Wd,
                   unsigned short* __restrict__ wbf) {
    const int t = blockIdx.x;   // 0 = d, 1 = a
    const int o = threadIdx.x;  // 0..255
    const float* W = (t == 0 ? Wd : Wa) + o * HH;
    unsigned short* dst = wbf + (t * HH + o) * KK;
    for (int e = 0; e < 152; ++e) dst[e] = f2bf(W[e]);
    float u = 0.f, c2 = 0.f, v = 0.f;
    for (int i = 76; i < 128; ++i) {
        const float d = exp2f(-(float)i * 0.10381025296523008f);  // 10^(-i/32)
        u  += d * W[2 * i];
        c2 += -0.5f * d * d * W[2 * i + 1];
        v  += W[2 * i + 1];
    }
    dst[152] = f2bf(u);
    dst[153] = f2bf(c2);
    dst[154] = f2bf(v);
    dst[155] = 0; dst[156] = 0; dst[157] = 0; dst[158] = 0; dst[159] = 0;
}

// E swizzle (R8-verified): 16B chunk ch of row r at byte r*512 + ((ch^(r&7))<<4).
// Row stride stays 512B (chunks 0..19 used, 20..31 dead) so the XOR-decomposed
// addressing carries over unchanged.

__global__ __launch_bounds__(512, 4)
void cgse_main(const float* __restrict__ points,
               const float* __restrict__ anchors,
               const unsigned short* __restrict__ wbf,
               const float* __restrict__ ba,
               const float* __restrict__ bd,
               float* __restrict__ out) {
    __shared__ __align__(16) unsigned short E[2][64 * HH];  // 64 KB dbuf
    __shared__ float dms[P_PTS][HH];                        // 8 KB d-pass maxes
    __shared__ float xs[2][P_PTS][64];                      // 4 KB
    __shared__ float anch[192];

    const int tid = threadIdx.x;
    const int wave = tid >> 6, lane = tid & 63;
    const int l5 = lane & 31, half = lane >> 5;
    const int base = blockIdx.x * P_PTS;
    const int col = wave * 32 + l5;  // this wave's output column (one of 256)

    // ---- anchors, then geometry: 512 tasks / 512 threads (pt = wave, k = lane)
    if (tid < 192) anch[tid] = anchors[tid];
    __syncthreads();
    {
        const int k2 = (lane + 1) & 63;
        const int pn = base + wave;
        const float px = points[pn * 3 + 0], py = points[pn * 3 + 1], pz = points[pn * 3 + 2];
        const float r1x = px - anch[lane * 3 + 0];
        const float r1y = py - anch[lane * 3 + 1];
        const float r1z = pz - anch[lane * 3 + 2];
        const float r2x = px - anch[k2 * 3 + 0];
        const float r2y = py - anch[k2 * 3 + 1];
        const float r2z = pz - anch[k2 * 3 + 2];
        xs[0][wave][lane] = sqrtf(r1x * r1x + r1y * r1y + r1z * r1z) * 5.0f;  // /SIGMA_D
        const float cx = r1y * r2z - r1z * r2y;
        const float cy = r1z * r2x - r1x * r2z;
        const float cz = r1x * r2y - r1y * r2x;
        const float sv = sqrtf(cx * cx + cy * cy + cz * cz);
        const float cv = r1x * r2x + r1y * r2y + r1z * r2z;
        xs[1][wave][lane] = atan2f(sv, cv) * 3.8197186342054885f;  // *180/(15*pi)
    }

    const float bias = ba[col] + bd[col];

    // fill constants: wave w fills chunks {w, w+8, w+16(w<4)}; chunk ch covers
    // pairs 4ch..4ch+3 (ch<=18); ch 19 = augmented [x, x^2, 1, 0...].
    // pair factor 10^(-4ch/32) = 10^(-w/8) * 10^(-ci), ci = ch>>3.
    const float cw = 0.15915494309189535f * __expf(-(float)wave * 0.2878231366242554f);

    // XOR-decomposed address bases (bytes)
    const int wbase = (lane << 9) ^ ((wave ^ (lane & 7)) << 4);  // fill: ^ (ci<<7)
    int rbase[2];
    rbase[0] = (l5 << 9) ^ ((l5 & 7) << 4) ^ (half << 4);        // read: ^ (ks<<5)
    rbase[1] = rbase[0] + (32 << 9);

    // fill one 16B chunk: row = lane, chunk = wave + 8*ci (ci compile-time).
    // x = raw index value; xc = x * cw. Revolutions < 10 << 256-rev domain.
    auto fill_chunk = [&](char* eb, int ci, float x, float xc) {
        uint4v w;
        if (wave == 3 && ci == 2) {           // chunk 19: [x, x^2, 1, 0...]
            w[0] = pack_sc(x, x * x);
            w[1] = pack_sc(1.0f, 0.0f);
            w[2] = 0u;
            w[3] = 0u;
        } else {
            const float DCI[3] = {1.0f, 0.1f, 0.01f};
            const float t0 = xc * DCI[ci];
            const float t[4] = {t0, t0 * 0.9305720409297085f,
                                t0 * 0.8659643233600653f, t0 * 0.8058421877614819f};
            #pragma unroll
            for (int j = 0; j < 4; ++j)
                w[j] = pack_sc(__builtin_amdgcn_sinf(t[j]), __builtin_amdgcn_cosf(t[j]));
        }
        *(uint4v*)(eb + (wbase ^ (ci << 7))) = w;
    };

    // ---- W strip (one type) in registers: 10 ks x short8 = 40 VGPRs
    short8 bw[10];
    auto loadW = [&](int t) {
        const unsigned short* wr = wbf + (t * HH + col) * KK + half * 8;
        #pragma unroll
        for (int ks = 0; ks < 10; ++ks)
            bw[ks] = *(const short8*)(wr + ks * 16);
    };

    loadW(0);
    __syncthreads();  // xs ready
    // prologue: fill buf0 for phase 0 (point 0, d-type)
    {
        const float x = xs[0][0][lane], xc = x * cw;
        fill_chunk((char*)E[0], 0, x, xc);
        fill_chunk((char*)E[0], 1, x, xc);
        if (wave < 4) fill_chunk((char*)E[0], 2, x, xc);
    }

    // 16 phases: 0..7 = d-pass (pt 0..7), 8..15 = a-pass (pt 0..7)
    #pragma unroll 1
    for (int ph = 0; ph < 16; ++ph) {
        __syncthreads();  // E[ph&1] filled; E[ph&1 ^1] free
        const int b = ph & 1;
        if (ph == 8) loadW(1);  // switch to Wa for the a-pass

        const bool dofill = (ph + 1) < 16;
        float xn = 0.f, xcn = 0.f;
        if (dofill) {
            const int pn = (ph + 1) & 7;
            xn = ((ph + 1) < 8 ? xs[0][pn][lane] : xs[1][pn][lane]);
            xcn = xn * cw;
        }

        const char* ebC = (const char*)E[b];
        char* ebN = (char*)E[b ^ 1];

        f32x16 acc[2];
        #pragma unroll
        for (int mt = 0; mt < 2; ++mt)
            #pragma unroll
            for (int r = 0; r < 16; ++r) acc[mt][r] = 0.f;

        #pragma unroll
        for (int ks = 0; ks < 10; ++ks) {
            if (dofill) {
                if (ks == 0) fill_chunk(ebN, 0, xn, xcn);
                if (ks == 4) fill_chunk(ebN, 1, xn, xcn);
                if (ks == 8 && wave < 4) fill_chunk(ebN, 2, xn, xcn);
            }
            #pragma unroll
            for (int mt = 0; mt < 2; ++mt) {
                const short8 afr = *(const short8*)(ebC + (rbase[mt] ^ (ks << 5)));
                acc[mt] = __builtin_amdgcn_mfma_f32_32x32x16_bf16(
                    afr, bw[ks], acc[mt], 0, 0, 0);
            }
        }

        // epilogue: max over 64 anchors. C layout: col=lane&31, rows split by
        // lane-half; 2 mt tiles x 16 regs cover 32 rows; shfl_down(32) merges
        // halves. Valid on lanes 0..31.
        const int q = ph & 7;
        float t8[8];
        #pragma unroll
        for (int r = 0; r < 8; ++r)
            t8[r] = fmaxf(fmaxf(acc[0][2 * r], acc[0][2 * r + 1]),
                          fmaxf(acc[1][2 * r], acc[1][2 * r + 1]));
        const float ta = fmaxf(fmaxf(t8[0], t8[1]), fmaxf(t8[2], t8[3]));
        const float tb = fmaxf(fmaxf(t8[4], t8[5]), fmaxf(t8[6], t8[7]));
        float m = fmaxf(ta, tb);
        m = fmaxf(m, __shfl_down(m, 32));
        if (lane < 32) {
            if (ph < 8) dms[q][col] = m;
            else out[(base + q) * HH + col] = m + dms[q][col] + bias;
        }
    }
}

extern "C" void kernel_launch(void* const* d_in, const int* in_sizes, int n_in,
                              void* d_out, int out_size, void* d_ws, size_t ws_size,
                              hipStream_t stream) {
    const float* points  = (const float*)d_in[0];
    const float* anchors = (const float*)d_in[1];
    // d_in[2] = cor_score: unused by the reference
    const float* Wa = (const float*)d_in[3];
    const float* ba = (const float*)d_in[4];
    const float* Wd = (const float*)d_in[5];
    const float* bd = (const float*)d_in[6];

    unsigned short* wbf = (unsigned short*)d_ws;  // 160 KB: trimmed+aug Wd|Wa bf16

    hipLaunchKernelGGL(prep_w_kernel, dim3(2), dim3(256), 0, stream, Wa, Wd, wbf);
    hipLaunchKernelGGL(cgse_main, dim3(NPTS / P_PTS), dim3(512), 0, stream,
                       points, anchors, wbf, ba, bd, (float*)d_out);
}

// Round 6
// 110.465 us; speedup vs baseline: 1.2244x; 1.0917x over previous
//
#include <hip/hip_runtime.h>
#include <hip/hip_bf16.h>
#include <math.h>

// CrossGeometricStructureEmbedding, round 13.
// R12 post-mortem: prediction matched exactly (48.5us; conflicts 5.24M =
// reads x 4cy; absmax unchanged -> Taylor fold invisible under bf16 noise).
// LDS read pipe still the leader (5MB/CU = 25.7us of 48.5). R13 compounds
// two cuts inside the proven schedule:
// (1) anchor-split: wave owns 64 cols x 32 anchors (hh = wave>>2); per ks
//     1 A-read feeds 2 MFMAs (was 1:1). Partial maxes per anchor-half merge
//     through dms/ams[2][q][col] at the top of phase q+9 using the EXISTING
//     barrier (one extra tail phase, zero extra barriers). R11's spill trap
//     is gone because K shrank: bw[2][7] = 56 regs.
// (2) Taylor cutoff 76 -> 52: 3rd-order sin / 4th-order cos fold pairs
//     52..127 into 5 augmented cols [x,x^2,x^3,x^4,1] (u1,u2,u3,u4,v in
//     prep). Worst z = x*10^(-52/32) ~ 0.85 -> err ~7e-4 < bf16 noise.
//     K: 160 -> 112 (7 ks). E row stride 256B (16-chunk XOR field, closure
//     and bank pattern preserved).
// Reads/wave/phase 20 -> 7; predict conflicts ~1.85M, kernel ~33-40us,
// WRITE_SIZE 4096 (no spill), VGPR ~110 <= 128 (4 waves/SIMD).

typedef __attribute__((ext_vector_type(8))) short short8;
typedef __attribute__((ext_vector_type(16))) float f32x16;
typedef __attribute__((ext_vector_type(4))) unsigned int uint4v;

#define HH 256
#define KK 112
#define P_PTS 8
#define NPTS 4096

__device__ __forceinline__ unsigned short f2bf(float f) {
    union { float f; unsigned int u; } v; v.f = f;
    unsigned int r = v.u + 0x7fffu + ((v.u >> 16) & 1u);  // RNE
    return (unsigned short)(r >> 16);
}

__device__ __forceinline__ unsigned int pack_sc(float s, float c) {
    union { __hip_bfloat162 h; unsigned int u; } v;
    v.h = __float22bfloat162_rn(make_float2(s, c));  // low = even elem, high = odd
    return v.u;
}

// Build trimmed+augmented W: wbf[(t*256+o)*112 + e]
//   e in [0,104): W[o][e] bf16 (pairs 0..51)
//   e=104..108: u1 (x), u2 (x^2), u3 (x^3), u4 (x^4), v (1); e in [109,112): 0
// sin(z) ~ z - z^3/6, cos(z) ~ 1 - z^2/2 + z^4/24 for z = x*d_i, i >= 52.
__global__ __launch_bounds__(256)
void prep_w_kernel(const float* __restrict__ Wa, const float* __restrict__ Wd,
                   unsigned short* __restrict__ wbf) {
    const int t = blockIdx.x;   // 0 = d, 1 = a
    const int o = threadIdx.x;  // 0..255
    const float* W = (t == 0 ? Wd : Wa) + o * HH;
    unsigned short* dst = wbf + (t * HH + o) * KK;
    for (int e = 0; e < 104; ++e) dst[e] = f2bf(W[e]);
    float u1 = 0.f, u2 = 0.f, u3 = 0.f, u4 = 0.f, v = 0.f;
    for (int i = 52; i < 128; ++i) {
        const float d = exp2f(-(float)i * 0.10381025296523008f);  // 10^(-i/32)
        const float d2 = d * d;
        const float ws = W[2 * i], wc = W[2 * i + 1];
        u1 += d * ws;
        u3 += -(d * d2) * (1.0f / 6.0f) * ws;
        u2 += -0.5f * d2 * wc;
        u4 += (d2 * d2) * (1.0f / 24.0f) * wc;
        v  += wc;
    }
    dst[104] = f2bf(u1);
    dst[105] = f2bf(u2);
    dst[106] = f2bf(u3);
    dst[107] = f2bf(u4);
    dst[108] = f2bf(v);
    dst[109] = 0; dst[110] = 0; dst[111] = 0;
}

// E swizzle: row stride 256B (16-chunk field); 16B chunk ch of row r at byte
//   r*256 + ((ch ^ (r&7)) << 4)
// XOR-decomposes (pure XOR algebra, fields may overlap):
//   (r<<8) ^ ((r&7)<<4) ^ (ch<<4). Closure: chunk groups [0..7],[8..15] are
// closed under low-3 XOR; banks same as R12's verified pattern (256r/4%32=0).

__global__ __launch_bounds__(512, 4)
void cgse_main(const float* __restrict__ points,
               const float* __restrict__ anchors,
               const unsigned short* __restrict__ wbf,
               const float* __restrict__ ba,
               const float* __restrict__ bd,
               float* __restrict__ out) {
    __shared__ __align__(16) unsigned short E[2][64 * 128];  // 32 KB dbuf (256B rows)
    __shared__ float dms[2][P_PTS][HH];                      // 16 KB d-pass half-maxes
    __shared__ float ams[2][P_PTS][HH];                      // 16 KB a-pass half-maxes
    __shared__ float xs[2][P_PTS][64];                       // 4 KB
    __shared__ float anch[192];

    const int tid = threadIdx.x;
    const int wave = tid >> 6, lane = tid & 63;
    const int l5 = lane & 31, half = lane >> 5;
    const int base = blockIdx.x * P_PTS;
    const int hh = wave >> 2;            // anchor half (0: rows 0..31, 1: 32..63)
    const int colb = (wave & 3) * 64;    // wave's 64-col group

    // ---- anchors, then geometry: 512 tasks / 512 threads (pt = wave, k = lane)
    if (tid < 192) anch[tid] = anchors[tid];
    __syncthreads();
    {
        const int k2 = (lane + 1) & 63;
        const int pn = base + wave;
        const float px = points[pn * 3 + 0], py = points[pn * 3 + 1], pz = points[pn * 3 + 2];
        const float r1x = px - anch[lane * 3 + 0];
        const float r1y = py - anch[lane * 3 + 1];
        const float r1z = pz - anch[lane * 3 + 2];
        const float r2x = px - anch[k2 * 3 + 0];
        const float r2y = py - anch[k2 * 3 + 1];
        const float r2z = pz - anch[k2 * 3 + 2];
        xs[0][wave][lane] = sqrtf(r1x * r1x + r1y * r1y + r1z * r1z) * 5.0f;  // /SIGMA_D
        const float cx = r1y * r2z - r1z * r2y;
        const float cy = r1z * r2x - r1x * r2z;
        const float cz = r1x * r2y - r1y * r2x;
        const float sv = sqrtf(cx * cx + cy * cy + cz * cz);
        const float cv = r1x * r2x + r1y * r2y + r1z * r2z;
        xs[1][wave][lane] = atan2f(sv, cv) * 3.8197186342054885f;  // *180/(15*pi)
    }

    // combine-phase bias (one col per thread, tid < 256)
    const float bias_c = (tid < HH) ? (ba[tid] + bd[tid]) : 0.0f;

    // fill constants: wave w fills chunk w and (w<6) chunk 8+w; chunk ch
    // covers pairs 4ch..4ch+3 (ch <= 12); ch 13 = augmented [x,x^2,x^3,x^4,1].
    // pair factor 10^(-4ch/32) = 10^(-w/8) * 10^(-c) for ch = w + 8c.
    const float cw = 0.15915494309189535f * __expf(-(float)wave * 0.2878231366242554f);

    // XOR-decomposed address bases (bytes)
    const int wbase = (lane << 8) ^ (((lane & 7) ^ wave) << 4);  // fill: ^ (c<<7)
    const int arow = hh * 32 + l5;                                // A-frag row (anchor)
    const int rbase = (arow << 8) ^ ((arow & 7) << 4) ^ (half << 4);  // read: ^ (ks<<5)

    // fill one 16B chunk: row = lane, chunk = wave + 8c (c compile-time).
    // Revolutions < 8 << 256-rev valid domain of v_sin/v_cos.
    auto fill_chunk = [&](char* eb, int c, float x, float xc) {
        uint4v w;
        if (wave == 5 && c == 1) {            // chunk 13: [x,x^2,x^3,x^4,1,0,0,0]
            const float x2 = x * x;
            w[0] = pack_sc(x, x2);
            w[1] = pack_sc(x2 * x, x2 * x2);
            w[2] = pack_sc(1.0f, 0.0f);
            w[3] = 0u;
        } else {
            const float t0 = c ? xc * 0.1f : xc;
            const float t[4] = {t0, t0 * 0.9305720409297085f,
                                t0 * 0.8659643233600653f, t0 * 0.8058421877614819f};
            #pragma unroll
            for (int j = 0; j < 4; ++j)
                w[j] = pack_sc(__builtin_amdgcn_sinf(t[j]), __builtin_amdgcn_cosf(t[j]));
        }
        *(uint4v*)(eb + (wbase ^ (c << 7))) = w;
    };

    // ---- W strips for the wave's 2 col-tiles: 2 x 7 x short8 = 56 VGPRs
    short8 bw[2][7];
    auto loadW = [&](int t) {
        #pragma unroll
        for (int ntp = 0; ntp < 2; ++ntp) {
            const unsigned short* wr =
                wbf + (t * HH + colb + ntp * 32 + l5) * KK + half * 8;
            #pragma unroll
            for (int ks = 0; ks < 7; ++ks)
                bw[ntp][ks] = *(const short8*)(wr + ks * 16);
        }
    };

    loadW(0);
    __syncthreads();  // xs ready
    // prologue: fill buf0 for phase 0 (point 0, d-type)
    {
        const float x = xs[0][0][lane], xc = x * cw;
        fill_chunk((char*)E[0], 0, x, xc);
        if (wave < 6) fill_chunk((char*)E[0], 1, x, xc);
    }

    // phases 0..7 = d-pass (pt 0..7), 8..15 = a-pass (pt 0..7),
    // combine+output for point ph-9 at top of phases 9..16.
    #pragma unroll 1
    for (int ph = 0; ph < 17; ++ph) {
        __syncthreads();  // E[ph&1] filled; E[ph&1^1] free; partials visible

        if (ph >= 9 && tid < HH) {  // combine point q = ph-9 (both types, both halves)
            const int q = ph - 9;
            out[(base + q) * HH + tid] =
                fmaxf(ams[0][q][tid], ams[1][q][tid]) +
                fmaxf(dms[0][q][tid], dms[1][q][tid]) + bias_c;
        }
        if (ph == 16) break;

        const int b = ph & 1;
        if (ph == 8) loadW(1);  // switch to Wa for the a-pass

        const bool dofill = (ph + 1) < 16;
        float xn = 0.f, xcn = 0.f;
        if (dofill) {
            const int pn = (ph + 1) & 7;
            xn = ((ph + 1) < 8 ? xs[0][pn][lane] : xs[1][pn][lane]);
            xcn = xn * cw;
        }

        const char* ebC = (const char*)E[b];
        char* ebN = (char*)E[b ^ 1];

        f32x16 acc[2];
        #pragma unroll
        for (int ntp = 0; ntp < 2; ++ntp)
            #pragma unroll
            for (int r = 0; r < 16; ++r) acc[ntp][r] = 0.f;

        #pragma unroll
        for (int ks = 0; ks < 7; ++ks) {
            if (dofill) {
                if (ks == 0) fill_chunk(ebN, 0, xn, xcn);
                if (ks == 3 && wave < 6) fill_chunk(ebN, 1, xn, xcn);
            }
            const short8 afr = *(const short8*)(ebC + (rbase ^ (ks << 5)));
            acc[0] = __builtin_amdgcn_mfma_f32_32x32x16_bf16(afr, bw[0][ks], acc[0], 0, 0, 0);
            acc[1] = __builtin_amdgcn_mfma_f32_32x32x16_bf16(afr, bw[1][ks], acc[1], 0, 0, 0);
        }

        // epilogue: per ntp, max over this wave's 32 anchors (16 regs cover 16
        // rows; shfl_down(32) merges lane-halves = other 16 rows of same col).
        // Valid on lanes 0..31; write to the (hh, q) partial slot.
        const int q = ph & 7;
        float (*pm)[P_PTS][HH] = (ph < 8) ? dms : ams;
        #pragma unroll
        for (int ntp = 0; ntp < 2; ++ntp) {
            float t8[8];
            #pragma unroll
            for (int r = 0; r < 8; ++r)
                t8[r] = fmaxf(acc[ntp][2 * r], acc[ntp][2 * r + 1]);
            const float ta = fmaxf(fmaxf(t8[0], t8[1]), fmaxf(t8[2], t8[3]));
            const float tb = fmaxf(fmaxf(t8[4], t8[5]), fmaxf(t8[6], t8[7]));
            float m = fmaxf(ta, tb);
            m = fmaxf(m, __shfl_down(m, 32));
            if (lane < 32) pm[hh][q][colb + ntp * 32 + l5] = m;
        }
    }
}

extern "C" void kernel_launch(void* const* d_in, const int* in_sizes, int n_in,
                              void* d_out, int out_size, void* d_ws, size_t ws_size,
                              hipStream_t stream) {
    const float* points  = (const float*)d_in[0];
    const float* anchors = (const float*)d_in[1];
    // d_in[2] = cor_score: unused by the reference
    const float* Wa = (const float*)d_in[3];
    const float* ba = (const float*)d_in[4];
    const float* Wd = (const float*)d_in[5];
    const float* bd = (const float*)d_in[6];

    unsigned short* wbf = (unsigned short*)d_ws;  // 112 KB: trimmed+aug Wd|Wa bf16

    hipLaunchKernelGGL(prep_w_kernel, dim3(2), dim3(256), 0, stream, Wa, Wd, wbf);
    hipLaunchKernelGGL(cgse_main, dim3(NPTS / P_PTS), dim3(512), 0, stream,
                       points, anchors, wbf, ba, bd, (float*)d_out);
}